// Round 2
// baseline (2070.263 us; speedup 1.0000x reference)
//
#include <hip/hip_runtime.h>
#include <math.h>

#define BATCH 8
#define NPTS 4096
#define CHAN 128
#define KNN 16

// ---------------------------------------------------------------------------
// Kernel 1: per-point 16-NN (fp32 d2, numpy-exact formula) + fp32 score with
// numpy's pairwise-summation order over (d, k):
//   per d: r_j = a_j + a_{j+8};  P_d = ((r0+r1)+(r2+r3)) + ((r4+r5)+(r6+r7))
//   score = ((P0 + P1) + P2)
// k-order = KNN rank order (ascending d2, stable ties -> lower index), which
// matches take_along_axis(nbr_idx) ordering in the reference.
// grid: BATCH * (NPTS/256), block 256. LDS: 4096 float4 (x,y,z,sq) = 64 KB.
// ---------------------------------------------------------------------------
__global__ __launch_bounds__(256) void knn_score_kernel(
    const float* __restrict__ x, float* __restrict__ score) {
  const int b = blockIdx.x / (NPTS / 256);
  const int nbase = (blockIdx.x % (NPTS / 256)) * 256;
  __shared__ float4 xs[NPTS];  // 64 KB: (x, y, z, sq)

  const float* xb = x + (size_t)b * 3 * NPTS;
  for (int i = threadIdx.x; i < NPTS; i += 256) {
    float px = xb[i];
    float py = xb[NPTS + i];
    float pz = xb[2 * NPTS + i];
    // sq like np.sum(x*x, axis=1): ((x0^2 + x1^2) + x2^2), fp32, no fma
    float sq = __fadd_rn(__fadd_rn(__fmul_rn(px, px), __fmul_rn(py, py)),
                         __fmul_rn(pz, pz));
    xs[i] = make_float4(px, py, pz, sq);
  }
  __syncthreads();

  const int n = nbase + threadIdx.x;
  const float4 p = xs[n];

  float d2v[KNN];
  int idxv[KNN];
#pragma unroll
  for (int j = 0; j < KNN; ++j) {
    d2v[j] = INFINITY;
    idxv[j] = 0;
  }

#pragma unroll 4
  for (int m = 0; m < NPTS; ++m) {
    float4 q = xs[m];
    // inner = ((x0*y0 + x1*y1) + x2*y2), fp32, no fma (numpy einsum order)
    float inner = __fadd_rn(
        __fadd_rn(__fmul_rn(p.x, q.x), __fmul_rn(p.y, q.y)),
        __fmul_rn(p.z, q.z));
    // d2 = (sq_n + sq_m) - 2*inner  (2*inner exact; subtraction rounded once)
    float d2 = __fsub_rn(__fadd_rn(p.w, q.w), __fmul_rn(2.0f, inner));
    // strict < : ties keep the earlier (lower) index first == stable argsort
    if (d2 < d2v[KNN - 1]) {
      float cd = d2;
      int ci = m;
      bool ins = false;
#pragma unroll
      for (int j = 0; j < KNN; ++j) {
        bool sw = ins || (cd < d2v[j]);
        if (sw) {
          float td = d2v[j]; int ti = idxv[j];
          d2v[j] = cd; idxv[j] = ci;
          cd = td; ci = ti;
          ins = true;
        }
      }
    }
  }

  // Gather neighbor coords in KNN-rank order.
  float nx[KNN], ny[KNN], nz[KNN];
#pragma unroll
  for (int j = 0; j < KNN; ++j) {
    float4 q = xs[idxv[j]];
    nx[j] = q.x; ny[j] = q.y; nz[j] = q.z;
  }

  // numpy fp32 pairwise sum over (3,16), k contiguous-inner, d sequential.
  float P[3];
#pragma unroll
  for (int d = 0; d < 3; ++d) {
    const float pc = (d == 0) ? p.x : ((d == 1) ? p.y : p.z);
    float r[8];
#pragma unroll
    for (int j = 0; j < 8; ++j) {
      float c0 = (d == 0) ? nx[j] : ((d == 1) ? ny[j] : nz[j]);
      float c1 = (d == 0) ? nx[j + 8] : ((d == 1) ? ny[j + 8] : nz[j + 8]);
      float e0 = __fsub_rn(c0, pc);
      float e1 = __fsub_rn(c1, pc);
      r[j] = __fadd_rn(__fmul_rn(e0, e0), __fmul_rn(e1, e1));
    }
    float t0 = __fadd_rn(r[0], r[1]);
    float t1 = __fadd_rn(r[2], r[3]);
    float t2 = __fadd_rn(r[4], r[5]);
    float t3 = __fadd_rn(r[6], r[7]);
    P[d] = __fadd_rn(__fadd_rn(t0, t1), __fadd_rn(t2, t3));
  }
  float s = __fadd_rn(__fadd_rn(P[0], P[1]), P[2]);
  score[(size_t)b * NPTS + n] = s;
}

// ---------------------------------------------------------------------------
// Kernel 2: counting rank on fp32 score bits.
// rank(n) = #{m : s[m]>s[n] or (s[m]==s[n] and m<n)}  == stable desc argsort.
// grid: BATCH * (NPTS/512), block 512. LDS: 4096 floats = 16 KB.
// ---------------------------------------------------------------------------
__global__ __launch_bounds__(512) void rank_kernel(
    const float* __restrict__ score, int* __restrict__ sel, int npts) {
  const int b = blockIdx.x / (NPTS / 512);
  const int nbase = (blockIdx.x % (NPTS / 512)) * 512;
  __shared__ float ss[NPTS];

  const float* sb = score + (size_t)b * NPTS;
  for (int i = threadIdx.x; i < NPTS; i += 512) ss[i] = sb[i];
  __syncthreads();

  const int n = nbase + threadIdx.x;
  const float sn = ss[n];
  int cnt = 0;
#pragma unroll 8
  for (int m = 0; m < NPTS; ++m) {
    float sm = ss[m];
    cnt += (sm > sn) || (sm == sn && m < n);
  }
  if (cnt < npts) sel[(size_t)b * npts + cnt] = n;
}

// ---------------------------------------------------------------------------
// Kernel 3: gather xyz then features into the concatenated flat output.
// ---------------------------------------------------------------------------
__global__ __launch_bounds__(256) void gather_kernel(
    const float* __restrict__ x, const float* __restrict__ y,
    const int* __restrict__ sel, float* __restrict__ out, int npts,
    int total0, int total) {
  int tid = blockIdx.x * blockDim.x + threadIdx.x;
  if (tid >= total) return;
  if (tid < total0) {
    // out0: (B, 3, npts)
    int j = tid % npts;
    int rest = tid / npts;
    int d = rest % 3;
    int b = rest / 3;
    int src = sel[b * npts + j];
    out[tid] = x[((size_t)b * 3 + d) * NPTS + src];
  } else {
    // out1: (B, C, npts)
    int t = tid - total0;
    int j = t % npts;
    int rest = t / npts;
    int c = rest % CHAN;
    int b = rest / CHAN;
    int src = sel[b * npts + j];
    out[tid] = y[((size_t)b * CHAN + c) * NPTS + src];
  }
}

extern "C" void kernel_launch(void* const* d_in, const int* in_sizes, int n_in,
                              void* d_out, int out_size, void* d_ws,
                              size_t ws_size, hipStream_t stream) {
  const float* x = (const float*)d_in[0];
  const float* y = (const float*)d_in[1];
  float* out = (float*)d_out;

  // out_size = B*3*npts + B*C*npts = B*(3+C)*npts
  const int npts = out_size / (BATCH * (3 + CHAN));

  float* score = (float*)d_ws;                                    // B*N f32
  int* sel = (int*)((char*)d_ws + sizeof(float) * BATCH * NPTS);  // B*npts

  knn_score_kernel<<<BATCH * (NPTS / 256), 256, 0, stream>>>(x, score);
  rank_kernel<<<BATCH * (NPTS / 512), 512, 0, stream>>>(score, sel, npts);

  const int total0 = BATCH * 3 * npts;
  const int total = out_size;
  gather_kernel<<<(total + 255) / 256, 256, 0, stream>>>(
      x, y, sel, out, npts, total0, total);
}

// Round 3
// 1220.848 us; speedup vs baseline: 1.6958x; 1.6958x over previous
//
#include <hip/hip_runtime.h>
#include <math.h>

#define BATCH 8
#define NPTS 4096
#define CHAN 128
#define KNN 16
#define SPLIT 4
#define CHUNK (NPTS / SPLIT)   // 1024 points, 16 KB LDS
#define RSPLIT 4
#define RCHUNK (NPTS / RSPLIT) // 1024 scores, 4 KB LDS

// ---------------------------------------------------------------------------
// Kernel 1a: per-chunk 16-NN partials.
// grid: BATCH * (NPTS/256) * SPLIT = 512 blocks, block 256, LDS 16 KB.
// Each thread owns point n, scans m in [s*CHUNK, (s+1)*CHUNK), keeps top-16
// (ascending d2, strict < insertion => stable ties -> lower index).
// Partials stored [b][s][j][n] so both writes here and reads in the merge
// kernel are coalesced across n.
// ---------------------------------------------------------------------------
__global__ __launch_bounds__(256) void knn_partial_kernel(
    const float* __restrict__ x, float* __restrict__ pd2,
    int* __restrict__ pidx) {
  const int s = blockIdx.x % SPLIT;
  const int ntile = (blockIdx.x / SPLIT) % (NPTS / 256);
  const int b = blockIdx.x / (SPLIT * (NPTS / 256));
  __shared__ float4 xs[CHUNK];  // (x, y, z, sq)

  const float* xb = x + (size_t)b * 3 * NPTS;
  for (int i = threadIdx.x; i < CHUNK; i += 256) {
    int gm = s * CHUNK + i;
    float px = xb[gm];
    float py = xb[NPTS + gm];
    float pz = xb[2 * NPTS + gm];
    float sq = __fadd_rn(__fadd_rn(__fmul_rn(px, px), __fmul_rn(py, py)),
                         __fmul_rn(pz, pz));
    xs[i] = make_float4(px, py, pz, sq);
  }

  const int n = ntile * 256 + threadIdx.x;
  float ppx = xb[n];
  float ppy = xb[NPTS + n];
  float ppz = xb[2 * NPTS + n];
  float psq = __fadd_rn(__fadd_rn(__fmul_rn(ppx, ppx), __fmul_rn(ppy, ppy)),
                        __fmul_rn(ppz, ppz));
  __syncthreads();

  float d2v[KNN];
  int idxv[KNN];
#pragma unroll
  for (int j = 0; j < KNN; ++j) {
    d2v[j] = INFINITY;
    idxv[j] = 0x7fffffff;
  }

#pragma unroll 4
  for (int mm = 0; mm < CHUNK; ++mm) {
    float4 q = xs[mm];
    // inner = ((x0*y0 + x1*y1) + x2*y2), fp32, no fma (numpy einsum order)
    float inner = __fadd_rn(
        __fadd_rn(__fmul_rn(ppx, q.x), __fmul_rn(ppy, q.y)),
        __fmul_rn(ppz, q.z));
    // d2 = (sq_n + sq_m) - 2*inner   (reference formula, pinned rounding)
    float d2 = __fsub_rn(__fadd_rn(psq, q.w), __fmul_rn(2.0f, inner));
    if (d2 < d2v[KNN - 1]) {
      float cd = d2;
      int ci = s * CHUNK + mm;
      bool ins = false;
#pragma unroll
      for (int j = 0; j < KNN; ++j) {
        bool sw = ins || (cd < d2v[j]);
        if (sw) {
          float td = d2v[j]; int ti = idxv[j];
          d2v[j] = cd; idxv[j] = ci;
          cd = td; ci = ti;
          ins = true;
        }
      }
    }
  }

#pragma unroll
  for (int j = 0; j < KNN; ++j) {
    size_t o = ((size_t)(b * SPLIT + s) * KNN + j) * NPTS + n;
    pd2[o] = d2v[j];
    pidx[o] = idxv[j];
  }
}

// ---------------------------------------------------------------------------
// Kernel 1b: merge SPLIT partial top-16 lists -> global top-16, then fp32
// score with numpy's pairwise order (validated in round 2).
// Candidates arrive (s asc, j asc): within any equal-d2 group arrival is
// idx-ascending, so strict-< insertion reproduces the stable tie-break.
// grid: BATCH*NPTS/256 = 128 blocks, block 256.
// ---------------------------------------------------------------------------
__global__ __launch_bounds__(256) void merge_score_kernel(
    const float* __restrict__ x, const float* __restrict__ pd2,
    const int* __restrict__ pidx, float* __restrict__ score) {
  const int b = blockIdx.x / (NPTS / 256);
  const int n = (blockIdx.x % (NPTS / 256)) * 256 + threadIdx.x;

  float d2v[KNN];
  int idxv[KNN];
#pragma unroll
  for (int j = 0; j < KNN; ++j) {
    d2v[j] = INFINITY;
    idxv[j] = 0x7fffffff;
  }

  for (int s = 0; s < SPLIT; ++s) {
#pragma unroll
    for (int j = 0; j < KNN; ++j) {
      size_t o = ((size_t)(b * SPLIT + s) * KNN + j) * NPTS + n;
      float cd = pd2[o];
      if (cd >= d2v[KNN - 1]) break;  // list is ascending: rest can't insert
      int ci = pidx[o];
      bool ins = false;
#pragma unroll
      for (int jj = 0; jj < KNN; ++jj) {
        bool sw = ins || (cd < d2v[jj]);
        if (sw) {
          float td = d2v[jj]; int ti = idxv[jj];
          d2v[jj] = cd; idxv[jj] = ci;
          cd = td; ci = ti;
          ins = true;
        }
      }
    }
  }

  const float* xb = x + (size_t)b * 3 * NPTS;
  float ppx = xb[n];
  float ppy = xb[NPTS + n];
  float ppz = xb[2 * NPTS + n];

  float nx[KNN], ny[KNN], nz[KNN];
#pragma unroll
  for (int j = 0; j < KNN; ++j) {
    int idx = idxv[j];
    nx[j] = xb[idx];
    ny[j] = xb[NPTS + idx];
    nz[j] = xb[2 * NPTS + idx];
  }

  // numpy fp32 pairwise sum over (3,16): per d, r_j = a_j + a_{j+8},
  // P_d = ((r0+r1)+(r2+r3)) + ((r4+r5)+(r6+r7)); score = (P0+P1)+P2.
  float P[3];
#pragma unroll
  for (int d = 0; d < 3; ++d) {
    const float pc = (d == 0) ? ppx : ((d == 1) ? ppy : ppz);
    float r[8];
#pragma unroll
    for (int j = 0; j < 8; ++j) {
      float c0 = (d == 0) ? nx[j] : ((d == 1) ? ny[j] : nz[j]);
      float c1 = (d == 0) ? nx[j + 8] : ((d == 1) ? ny[j + 8] : nz[j + 8]);
      float e0 = __fsub_rn(c0, pc);
      float e1 = __fsub_rn(c1, pc);
      r[j] = __fadd_rn(__fmul_rn(e0, e0), __fmul_rn(e1, e1));
    }
    float t0 = __fadd_rn(r[0], r[1]);
    float t1 = __fadd_rn(r[2], r[3]);
    float t2 = __fadd_rn(r[4], r[5]);
    float t3 = __fadd_rn(r[6], r[7]);
    P[d] = __fadd_rn(__fadd_rn(t0, t1), __fadd_rn(t2, t3));
  }
  score[(size_t)b * NPTS + n] =
      __fadd_rn(__fadd_rn(P[0], P[1]), P[2]);
}

// ---------------------------------------------------------------------------
// Kernel 2a: zero the rank counters (kernel instead of memset: capture-safe).
// ---------------------------------------------------------------------------
__global__ __launch_bounds__(256) void zero_kernel(int* __restrict__ cnt) {
  cnt[blockIdx.x * 256 + threadIdx.x] = 0;
}

// ---------------------------------------------------------------------------
// Kernel 2b: partial counting rank over an m-chunk, atomicAdd into cnt.
// rank(n) = #{m : s[m]>s[n] or (s[m]==s[n] and m<n)} == stable desc argsort.
// grid: BATCH*(NPTS/256)*RSPLIT = 512 blocks, block 256, LDS 4 KB.
// ---------------------------------------------------------------------------
__global__ __launch_bounds__(256) void rank_partial_kernel(
    const float* __restrict__ score, int* __restrict__ cnt) {
  const int s = blockIdx.x % RSPLIT;
  const int ntile = (blockIdx.x / RSPLIT) % (NPTS / 256);
  const int b = blockIdx.x / (RSPLIT * (NPTS / 256));
  __shared__ float ss[RCHUNK];

  const float* sb = score + (size_t)b * NPTS;
  for (int i = threadIdx.x; i < RCHUNK; i += 256)
    ss[i] = sb[s * RCHUNK + i];

  const int n = ntile * 256 + threadIdx.x;
  const float sn = sb[n];
  __syncthreads();

  int c = 0;
#pragma unroll 8
  for (int mm = 0; mm < RCHUNK; ++mm) {
    float sm = ss[mm];
    int gm = s * RCHUNK + mm;
    c += (sm > sn) || (sm == sn && gm < n);
  }
  atomicAdd(&cnt[(size_t)b * NPTS + n], c);
}

// ---------------------------------------------------------------------------
// Kernel 2c: scatter selected points into rank order.
// ---------------------------------------------------------------------------
__global__ __launch_bounds__(256) void rank_scatter_kernel(
    const int* __restrict__ cnt, int* __restrict__ sel, int npts) {
  int t = blockIdx.x * 256 + threadIdx.x;  // over BATCH*NPTS
  int b = t / NPTS;
  int n = t % NPTS;
  int c = cnt[t];
  if (c < npts) sel[(size_t)b * npts + c] = n;
}

// ---------------------------------------------------------------------------
// Kernel 3: gather xyz then features into the concatenated flat output.
// ---------------------------------------------------------------------------
__global__ __launch_bounds__(256) void gather_kernel(
    const float* __restrict__ x, const float* __restrict__ y,
    const int* __restrict__ sel, float* __restrict__ out, int npts,
    int total0, int total) {
  int tid = blockIdx.x * blockDim.x + threadIdx.x;
  if (tid >= total) return;
  if (tid < total0) {
    int j = tid % npts;
    int rest = tid / npts;
    int d = rest % 3;
    int b = rest / 3;
    int src = sel[b * npts + j];
    out[tid] = x[((size_t)b * 3 + d) * NPTS + src];
  } else {
    int t = tid - total0;
    int j = t % npts;
    int rest = t / npts;
    int c = rest % CHAN;
    int b = rest / CHAN;
    int src = sel[b * npts + j];
    out[tid] = y[((size_t)b * CHAN + c) * NPTS + src];
  }
}

extern "C" void kernel_launch(void* const* d_in, const int* in_sizes, int n_in,
                              void* d_out, int out_size, void* d_ws,
                              size_t ws_size, hipStream_t stream) {
  const float* x = (const float*)d_in[0];
  const float* y = (const float*)d_in[1];
  float* out = (float*)d_out;

  const int npts = out_size / (BATCH * (3 + CHAN));

  // workspace layout (bytes):
  char* w = (char*)d_ws;
  float* pd2 = (float*)w;                    // B*S*16*N f32 = 8.39 MB
  w += sizeof(float) * (size_t)BATCH * SPLIT * KNN * NPTS;
  int* pidx = (int*)w;                       // B*S*16*N i32 = 8.39 MB
  w += sizeof(int) * (size_t)BATCH * SPLIT * KNN * NPTS;
  float* score = (float*)w;                  // B*N f32
  w += sizeof(float) * (size_t)BATCH * NPTS;
  int* cnt = (int*)w;                        // B*N i32
  w += sizeof(int) * (size_t)BATCH * NPTS;
  int* sel = (int*)w;                        // B*npts i32

  zero_kernel<<<BATCH * NPTS / 256, 256, 0, stream>>>(cnt);
  knn_partial_kernel<<<BATCH * (NPTS / 256) * SPLIT, 256, 0, stream>>>(
      x, pd2, pidx);
  merge_score_kernel<<<BATCH * NPTS / 256, 256, 0, stream>>>(
      x, pd2, pidx, score);
  rank_partial_kernel<<<BATCH * (NPTS / 256) * RSPLIT, 256, 0, stream>>>(
      score, cnt);
  rank_scatter_kernel<<<BATCH * NPTS / 256, 256, 0, stream>>>(cnt, sel, npts);

  const int total0 = BATCH * 3 * npts;
  gather_kernel<<<(out_size + 255) / 256, 256, 0, stream>>>(
      x, y, sel, out, npts, total0, out_size);
}

// Round 4
// 1089.513 us; speedup vs baseline: 1.9002x; 1.1205x over previous
//
#include <hip/hip_runtime.h>
#include <math.h>

#define BATCH 8
#define NPTS 4096
#define CHAN 128
#define KNN 16
#define SPLIT 4
#define CHUNK (NPTS / SPLIT)   // 1024 points, 16 KB LDS
#define RSPLIT 4
#define RCHUNK (NPTS / RSPLIT) // 1024 scores, 4 KB LDS

typedef unsigned long long u64;

// Monotone key: ascending u64 == (d2 ascending, idx ascending).
// Ties in d2 break toward lower index == lax.top_k stable order.
__device__ __forceinline__ u64 pack_key(float d2, int idx) {
  unsigned b = __float_as_uint(d2);
  b ^= (unsigned)((int)b >> 31) | 0x80000000u;  // order-preserving fp32 map
  return ((u64)b << 32) | (unsigned)idx;
}

// Branchless sorted insert into scalar registers k0..k15 (ascending).
// In-place descending update: each step reads only not-yet-written slots.
#define INSERT_KU(ku)                                                     \
  if ((ku) < k15) {                                                       \
    k15 = ((ku) < k14) ? k14 : (((ku) < k15) ? (ku) : k15);               \
    k14 = ((ku) < k13) ? k13 : (((ku) < k14) ? (ku) : k14);               \
    k13 = ((ku) < k12) ? k12 : (((ku) < k13) ? (ku) : k13);               \
    k12 = ((ku) < k11) ? k11 : (((ku) < k12) ? (ku) : k12);               \
    k11 = ((ku) < k10) ? k10 : (((ku) < k11) ? (ku) : k11);               \
    k10 = ((ku) < k9) ? k9 : (((ku) < k10) ? (ku) : k10);                 \
    k9 = ((ku) < k8) ? k8 : (((ku) < k9) ? (ku) : k9);                    \
    k8 = ((ku) < k7) ? k7 : (((ku) < k8) ? (ku) : k8);                    \
    k7 = ((ku) < k6) ? k6 : (((ku) < k7) ? (ku) : k7);                    \
    k6 = ((ku) < k5) ? k5 : (((ku) < k6) ? (ku) : k6);                    \
    k5 = ((ku) < k4) ? k4 : (((ku) < k5) ? (ku) : k5);                    \
    k4 = ((ku) < k3) ? k3 : (((ku) < k4) ? (ku) : k4);                    \
    k3 = ((ku) < k2) ? k2 : (((ku) < k3) ? (ku) : k3);                    \
    k2 = ((ku) < k1) ? k1 : (((ku) < k2) ? (ku) : k2);                    \
    k1 = ((ku) < k0) ? k0 : (((ku) < k1) ? (ku) : k1);                    \
    k0 = ((ku) < k0) ? (ku) : k0;                                         \
  }

#define DECL_KEYS                                                         \
  u64 k0 = ~0ull, k1 = ~0ull, k2 = ~0ull, k3 = ~0ull, k4 = ~0ull,         \
      k5 = ~0ull, k6 = ~0ull, k7 = ~0ull, k8 = ~0ull, k9 = ~0ull,         \
      k10 = ~0ull, k11 = ~0ull, k12 = ~0ull, k13 = ~0ull, k14 = ~0ull,    \
      k15 = ~0ull

// ---------------------------------------------------------------------------
// Kernel 1a: per-chunk 16-NN partials as sorted u64 keys.
// grid: BATCH * (NPTS/256) * SPLIT = 512 blocks, block 256, LDS 16 KB.
// Partials stored [b][s][j][n]: coalesced across n for write and read.
// ---------------------------------------------------------------------------
__global__ __launch_bounds__(256) void knn_partial_kernel(
    const float* __restrict__ x, u64* __restrict__ pkey) {
  const int s = blockIdx.x % SPLIT;
  const int ntile = (blockIdx.x / SPLIT) % (NPTS / 256);
  const int b = blockIdx.x / (SPLIT * (NPTS / 256));
  __shared__ float4 xs[CHUNK];  // (x, y, z, sq)

  const float* xb = x + (size_t)b * 3 * NPTS;
  for (int i = threadIdx.x; i < CHUNK; i += 256) {
    int gm = s * CHUNK + i;
    float px = xb[gm];
    float py = xb[NPTS + gm];
    float pz = xb[2 * NPTS + gm];
    float sq = __fadd_rn(__fadd_rn(__fmul_rn(px, px), __fmul_rn(py, py)),
                         __fmul_rn(pz, pz));
    xs[i] = make_float4(px, py, pz, sq);
  }

  const int n = ntile * 256 + threadIdx.x;
  float ppx = xb[n];
  float ppy = xb[NPTS + n];
  float ppz = xb[2 * NPTS + n];
  float psq = __fadd_rn(__fadd_rn(__fmul_rn(ppx, ppx), __fmul_rn(ppy, ppy)),
                        __fmul_rn(ppz, ppz));
  __syncthreads();

  DECL_KEYS;

#pragma unroll 4
  for (int mm = 0; mm < CHUNK; ++mm) {
    float4 q = xs[mm];
    // inner = ((x0*y0 + x1*y1) + x2*y2), fp32, no fma (numpy einsum order)
    float inner = __fadd_rn(
        __fadd_rn(__fmul_rn(ppx, q.x), __fmul_rn(ppy, q.y)),
        __fmul_rn(ppz, q.z));
    // d2 = (sq_n + sq_m) - 2*inner  (reference formula, pinned rounding)
    float d2 = __fsub_rn(__fadd_rn(psq, q.w), __fmul_rn(2.0f, inner));
    u64 ku = pack_key(d2, s * CHUNK + mm);
    INSERT_KU(ku);
  }

  u64* pb = pkey + ((size_t)(b * SPLIT + s) * KNN) * NPTS + n;
  pb[0 * NPTS] = k0;   pb[1 * NPTS] = k1;   pb[2 * NPTS] = k2;
  pb[3 * NPTS] = k3;   pb[4 * NPTS] = k4;   pb[5 * NPTS] = k5;
  pb[6 * NPTS] = k6;   pb[7 * NPTS] = k7;   pb[8 * NPTS] = k8;
  pb[9 * NPTS] = k9;   pb[10 * NPTS] = k10; pb[11 * NPTS] = k11;
  pb[12 * NPTS] = k12; pb[13 * NPTS] = k13; pb[14 * NPTS] = k14;
  pb[15 * NPTS] = k15;
}

// ---------------------------------------------------------------------------
// Kernel 1b: merge SPLIT sorted key lists -> global top-16, then fp32 score
// with numpy's pairwise order (validated round 2). Keys are unique, so
// insertion order is irrelevant to the final sorted set — exactness holds.
// grid: BATCH*NPTS/256 = 128 blocks, block 256.
// ---------------------------------------------------------------------------
__global__ __launch_bounds__(256) void merge_score_kernel(
    const float* __restrict__ x, const u64* __restrict__ pkey,
    float* __restrict__ score) {
  const int b = blockIdx.x / (NPTS / 256);
  const int n = (blockIdx.x % (NPTS / 256)) * 256 + threadIdx.x;

  DECL_KEYS;

#pragma unroll
  for (int s = 0; s < SPLIT; ++s) {
    const u64* pb = pkey + ((size_t)(b * SPLIT + s) * KNN) * NPTS + n;
#pragma unroll
    for (int j = 0; j < KNN; ++j) {
      u64 ku = pb[(size_t)j * NPTS];
      INSERT_KU(ku);
    }
  }

  int idxv[KNN];
  idxv[0] = (int)(unsigned)k0;   idxv[1] = (int)(unsigned)k1;
  idxv[2] = (int)(unsigned)k2;   idxv[3] = (int)(unsigned)k3;
  idxv[4] = (int)(unsigned)k4;   idxv[5] = (int)(unsigned)k5;
  idxv[6] = (int)(unsigned)k6;   idxv[7] = (int)(unsigned)k7;
  idxv[8] = (int)(unsigned)k8;   idxv[9] = (int)(unsigned)k9;
  idxv[10] = (int)(unsigned)k10; idxv[11] = (int)(unsigned)k11;
  idxv[12] = (int)(unsigned)k12; idxv[13] = (int)(unsigned)k13;
  idxv[14] = (int)(unsigned)k14; idxv[15] = (int)(unsigned)k15;

  const float* xb = x + (size_t)b * 3 * NPTS;
  float ppx = xb[n];
  float ppy = xb[NPTS + n];
  float ppz = xb[2 * NPTS + n];

  float nx[KNN], ny[KNN], nz[KNN];
#pragma unroll
  for (int j = 0; j < KNN; ++j) {
    int idx = idxv[j];
    nx[j] = xb[idx];
    ny[j] = xb[NPTS + idx];
    nz[j] = xb[2 * NPTS + idx];
  }

  // numpy fp32 pairwise sum over (3,16): per d, r_j = a_j + a_{j+8},
  // P_d = ((r0+r1)+(r2+r3)) + ((r4+r5)+(r6+r7)); score = (P0+P1)+P2.
  float P[3];
#pragma unroll
  for (int d = 0; d < 3; ++d) {
    const float pc = (d == 0) ? ppx : ((d == 1) ? ppy : ppz);
    float r[8];
#pragma unroll
    for (int j = 0; j < 8; ++j) {
      float c0 = (d == 0) ? nx[j] : ((d == 1) ? ny[j] : nz[j]);
      float c1 = (d == 0) ? nx[j + 8] : ((d == 1) ? ny[j + 8] : nz[j + 8]);
      float e0 = __fsub_rn(c0, pc);
      float e1 = __fsub_rn(c1, pc);
      r[j] = __fadd_rn(__fmul_rn(e0, e0), __fmul_rn(e1, e1));
    }
    float t0 = __fadd_rn(r[0], r[1]);
    float t1 = __fadd_rn(r[2], r[3]);
    float t2 = __fadd_rn(r[4], r[5]);
    float t3 = __fadd_rn(r[6], r[7]);
    P[d] = __fadd_rn(__fadd_rn(t0, t1), __fadd_rn(t2, t3));
  }
  score[(size_t)b * NPTS + n] =
      __fadd_rn(__fadd_rn(P[0], P[1]), P[2]);
}

// ---------------------------------------------------------------------------
// Kernel 2a: zero the rank counters (kernel instead of memset: capture-safe).
// ---------------------------------------------------------------------------
__global__ __launch_bounds__(256) void zero_kernel(int* __restrict__ cnt) {
  cnt[blockIdx.x * 256 + threadIdx.x] = 0;
}

// ---------------------------------------------------------------------------
// Kernel 2b: partial counting rank over an m-chunk, atomicAdd into cnt.
// rank(n) = #{m : s[m]>s[n] or (s[m]==s[n] and m<n)} == stable desc argsort.
// ---------------------------------------------------------------------------
__global__ __launch_bounds__(256) void rank_partial_kernel(
    const float* __restrict__ score, int* __restrict__ cnt) {
  const int s = blockIdx.x % RSPLIT;
  const int ntile = (blockIdx.x / RSPLIT) % (NPTS / 256);
  const int b = blockIdx.x / (RSPLIT * (NPTS / 256));
  __shared__ float ss[RCHUNK];

  const float* sb = score + (size_t)b * NPTS;
  for (int i = threadIdx.x; i < RCHUNK; i += 256)
    ss[i] = sb[s * RCHUNK + i];

  const int n = ntile * 256 + threadIdx.x;
  const float sn = sb[n];
  __syncthreads();

  int c = 0;
#pragma unroll 8
  for (int mm = 0; mm < RCHUNK; ++mm) {
    float sm = ss[mm];
    int gm = s * RCHUNK + mm;
    c += (sm > sn) || (sm == sn && gm < n);
  }
  atomicAdd(&cnt[(size_t)b * NPTS + n], c);
}

// ---------------------------------------------------------------------------
// Kernel 2c: scatter selected points into rank order.
// ---------------------------------------------------------------------------
__global__ __launch_bounds__(256) void rank_scatter_kernel(
    const int* __restrict__ cnt, int* __restrict__ sel, int npts) {
  int t = blockIdx.x * 256 + threadIdx.x;  // over BATCH*NPTS
  int b = t / NPTS;
  int n = t % NPTS;
  int c = cnt[t];
  if (c < npts) sel[(size_t)b * npts + c] = n;
}

// ---------------------------------------------------------------------------
// Kernel 3: gather xyz then features into the concatenated flat output.
// ---------------------------------------------------------------------------
__global__ __launch_bounds__(256) void gather_kernel(
    const float* __restrict__ x, const float* __restrict__ y,
    const int* __restrict__ sel, float* __restrict__ out, int npts,
    int total0, int total) {
  int tid = blockIdx.x * blockDim.x + threadIdx.x;
  if (tid >= total) return;
  if (tid < total0) {
    int j = tid % npts;
    int rest = tid / npts;
    int d = rest % 3;
    int b = rest / 3;
    int src = sel[b * npts + j];
    out[tid] = x[((size_t)b * 3 + d) * NPTS + src];
  } else {
    int t = tid - total0;
    int j = t % npts;
    int rest = t / npts;
    int c = rest % CHAN;
    int b = rest / CHAN;
    int src = sel[b * npts + j];
    out[tid] = y[((size_t)b * CHAN + c) * NPTS + src];
  }
}

extern "C" void kernel_launch(void* const* d_in, const int* in_sizes, int n_in,
                              void* d_out, int out_size, void* d_ws,
                              size_t ws_size, hipStream_t stream) {
  const float* x = (const float*)d_in[0];
  const float* y = (const float*)d_in[1];
  float* out = (float*)d_out;

  const int npts = out_size / (BATCH * (3 + CHAN));

  // workspace layout:
  char* w = (char*)d_ws;
  u64* pkey = (u64*)w;                       // B*S*16*N u64 = 16.78 MB
  w += sizeof(u64) * (size_t)BATCH * SPLIT * KNN * NPTS;
  float* score = (float*)w;                  // B*N f32
  w += sizeof(float) * (size_t)BATCH * NPTS;
  int* cnt = (int*)w;                        // B*N i32
  w += sizeof(int) * (size_t)BATCH * NPTS;
  int* sel = (int*)w;                        // B*npts i32

  zero_kernel<<<BATCH * NPTS / 256, 256, 0, stream>>>(cnt);
  knn_partial_kernel<<<BATCH * (NPTS / 256) * SPLIT, 256, 0, stream>>>(
      x, pkey);
  merge_score_kernel<<<BATCH * NPTS / 256, 256, 0, stream>>>(x, pkey, score);
  rank_partial_kernel<<<BATCH * (NPTS / 256) * RSPLIT, 256, 0, stream>>>(
      score, cnt);
  rank_scatter_kernel<<<BATCH * NPTS / 256, 256, 0, stream>>>(cnt, sel, npts);

  const int total0 = BATCH * 3 * npts;
  gather_kernel<<<(out_size + 255) / 256, 256, 0, stream>>>(
      x, y, sel, out, npts, total0, out_size);
}

// Round 5
// 520.850 us; speedup vs baseline: 3.9748x; 2.0918x over previous
//
#include <hip/hip_runtime.h>
#include <math.h>

#define BATCH 8
#define NPTS 4096
#define CHAN 128
#define KNN 16
#define SPLIT 4
#define CHUNK (NPTS / SPLIT)   // 1024 points, 16 KB LDS
#define RSPLIT 4
#define RCHUNK (NPTS / RSPLIT) // 1024 scores, 4 KB LDS

typedef unsigned long long u64;

// Monotone key: ascending u64 == (d2 ascending, idx ascending).
// Ties in d2 break toward lower index == lax.top_k stable order.
__device__ __forceinline__ u64 pack_key(float d2, int idx) {
  unsigned b = __float_as_uint(d2);
  b ^= (unsigned)((int)b >> 31) | 0x80000000u;  // order-preserving fp32 map
  return ((u64)b << 32) | (unsigned)idx;
}

// Fully branchless sorted insert (ascending k0..k15). All compares up front
// (reused lane masks), then pure select chains — no control flow, nothing
// for the register allocator to sink to scratch.
// Slot update reads only not-yet-written slots (descending order).
#define INSERT_KU(ku)                                                     \
  do {                                                                    \
    const u64 _u = (ku);                                                  \
    bool c0 = _u < k0, c1 = _u < k1, c2 = _u < k2, c3 = _u < k3;          \
    bool c4 = _u < k4, c5 = _u < k5, c6 = _u < k6, c7 = _u < k7;          \
    bool c8 = _u < k8, c9 = _u < k9, c10 = _u < k10, c11 = _u < k11;      \
    bool c12 = _u < k12, c13 = _u < k13, c14 = _u < k14, c15 = _u < k15;  \
    k15 = c14 ? k14 : (c15 ? _u : k15);                                   \
    k14 = c13 ? k13 : (c14 ? _u : k14);                                   \
    k13 = c12 ? k12 : (c13 ? _u : k13);                                   \
    k12 = c11 ? k11 : (c12 ? _u : k12);                                   \
    k11 = c10 ? k10 : (c11 ? _u : k11);                                   \
    k10 = c9 ? k9 : (c10 ? _u : k10);                                     \
    k9 = c8 ? k8 : (c9 ? _u : k9);                                        \
    k8 = c7 ? k7 : (c8 ? _u : k8);                                        \
    k7 = c6 ? k6 : (c7 ? _u : k7);                                        \
    k6 = c5 ? k5 : (c6 ? _u : k6);                                        \
    k5 = c4 ? k4 : (c5 ? _u : k5);                                        \
    k4 = c3 ? k3 : (c4 ? _u : k4);                                        \
    k3 = c2 ? k2 : (c3 ? _u : k3);                                        \
    k2 = c1 ? k1 : (c2 ? _u : k2);                                        \
    k1 = c0 ? k0 : (c1 ? _u : k1);                                        \
    k0 = c0 ? _u : k0;                                                    \
  } while (0)

#define DECL_KEYS                                                         \
  u64 k0 = ~0ull, k1 = ~0ull, k2 = ~0ull, k3 = ~0ull, k4 = ~0ull,         \
      k5 = ~0ull, k6 = ~0ull, k7 = ~0ull, k8 = ~0ull, k9 = ~0ull,         \
      k10 = ~0ull, k11 = ~0ull, k12 = ~0ull, k13 = ~0ull, k14 = ~0ull,    \
      k15 = ~0ull

// ---------------------------------------------------------------------------
// Kernel 1a: per-chunk 16-NN partials as sorted u64 keys.
// grid: BATCH * (NPTS/256) * SPLIT = 512 blocks = 2 blocks/CU = 2 waves/EU.
// __launch_bounds__(256, 2): min 2 waves/EU -> VGPR budget 256, NO SPILLS
// (rounds 3-4 spilled the 16-key state at default occupancy targeting).
// ---------------------------------------------------------------------------
__global__ __launch_bounds__(256, 2) void knn_partial_kernel(
    const float* __restrict__ x, u64* __restrict__ pkey) {
  const int s = blockIdx.x % SPLIT;
  const int ntile = (blockIdx.x / SPLIT) % (NPTS / 256);
  const int b = blockIdx.x / (SPLIT * (NPTS / 256));
  __shared__ float4 xs[CHUNK];  // (x, y, z, sq)

  const float* xb = x + (size_t)b * 3 * NPTS;
  for (int i = threadIdx.x; i < CHUNK; i += 256) {
    int gm = s * CHUNK + i;
    float px = xb[gm];
    float py = xb[NPTS + gm];
    float pz = xb[2 * NPTS + gm];
    float sq = __fadd_rn(__fadd_rn(__fmul_rn(px, px), __fmul_rn(py, py)),
                         __fmul_rn(pz, pz));
    xs[i] = make_float4(px, py, pz, sq);
  }

  const int n = ntile * 256 + threadIdx.x;
  float ppx = xb[n];
  float ppy = xb[NPTS + n];
  float ppz = xb[2 * NPTS + n];
  float psq = __fadd_rn(__fadd_rn(__fmul_rn(ppx, ppx), __fmul_rn(ppy, ppy)),
                        __fmul_rn(ppz, ppz));
  __syncthreads();

  DECL_KEYS;

#pragma unroll 2
  for (int mm = 0; mm < CHUNK; ++mm) {
    float4 q = xs[mm];
    // inner = ((x0*y0 + x1*y1) + x2*y2), fp32, no fma (numpy einsum order)
    float inner = __fadd_rn(
        __fadd_rn(__fmul_rn(ppx, q.x), __fmul_rn(ppy, q.y)),
        __fmul_rn(ppz, q.z));
    // d2 = (sq_n + sq_m) - 2*inner  (reference formula, pinned rounding)
    float d2 = __fsub_rn(__fadd_rn(psq, q.w), __fmul_rn(2.0f, inner));
    u64 ku = pack_key(d2, s * CHUNK + mm);
    INSERT_KU(ku);
  }

  u64* pb = pkey + ((size_t)(b * SPLIT + s) * KNN) * NPTS + n;
  pb[0 * NPTS] = k0;   pb[1 * NPTS] = k1;   pb[2 * NPTS] = k2;
  pb[3 * NPTS] = k3;   pb[4 * NPTS] = k4;   pb[5 * NPTS] = k5;
  pb[6 * NPTS] = k6;   pb[7 * NPTS] = k7;   pb[8 * NPTS] = k8;
  pb[9 * NPTS] = k9;   pb[10 * NPTS] = k10; pb[11 * NPTS] = k11;
  pb[12 * NPTS] = k12; pb[13 * NPTS] = k13; pb[14 * NPTS] = k14;
  pb[15 * NPTS] = k15;
}

// ---------------------------------------------------------------------------
// Kernel 1b: merge SPLIT sorted key lists -> global top-16, then fp32 score
// with numpy's pairwise order (validated round 2). Keys unique -> insertion
// order irrelevant -> exactness holds.
// grid: BATCH*NPTS/256 = 128 blocks, block 256, min 1 wave/EU (no spills).
// ---------------------------------------------------------------------------
__global__ __launch_bounds__(256, 1) void merge_score_kernel(
    const float* __restrict__ x, const u64* __restrict__ pkey,
    float* __restrict__ score) {
  const int b = blockIdx.x / (NPTS / 256);
  const int n = (blockIdx.x % (NPTS / 256)) * 256 + threadIdx.x;

  DECL_KEYS;

#pragma unroll
  for (int s = 0; s < SPLIT; ++s) {
    const u64* pb = pkey + ((size_t)(b * SPLIT + s) * KNN) * NPTS + n;
#pragma unroll
    for (int j = 0; j < KNN; ++j) {
      u64 ku = pb[(size_t)j * NPTS];
      INSERT_KU(ku);
    }
  }

  int idxv[KNN];
  idxv[0] = (int)(unsigned)k0;   idxv[1] = (int)(unsigned)k1;
  idxv[2] = (int)(unsigned)k2;   idxv[3] = (int)(unsigned)k3;
  idxv[4] = (int)(unsigned)k4;   idxv[5] = (int)(unsigned)k5;
  idxv[6] = (int)(unsigned)k6;   idxv[7] = (int)(unsigned)k7;
  idxv[8] = (int)(unsigned)k8;   idxv[9] = (int)(unsigned)k9;
  idxv[10] = (int)(unsigned)k10; idxv[11] = (int)(unsigned)k11;
  idxv[12] = (int)(unsigned)k12; idxv[13] = (int)(unsigned)k13;
  idxv[14] = (int)(unsigned)k14; idxv[15] = (int)(unsigned)k15;

  const float* xb = x + (size_t)b * 3 * NPTS;
  float ppx = xb[n];
  float ppy = xb[NPTS + n];
  float ppz = xb[2 * NPTS + n];

  float nx[KNN], ny[KNN], nz[KNN];
#pragma unroll
  for (int j = 0; j < KNN; ++j) {
    int idx = idxv[j];
    nx[j] = xb[idx];
    ny[j] = xb[NPTS + idx];
    nz[j] = xb[2 * NPTS + idx];
  }

  // numpy fp32 pairwise sum over (3,16): per d, r_j = a_j + a_{j+8},
  // P_d = ((r0+r1)+(r2+r3)) + ((r4+r5)+(r6+r7)); score = (P0+P1)+P2.
  float P[3];
#pragma unroll
  for (int d = 0; d < 3; ++d) {
    const float pc = (d == 0) ? ppx : ((d == 1) ? ppy : ppz);
    float r[8];
#pragma unroll
    for (int j = 0; j < 8; ++j) {
      float c0 = (d == 0) ? nx[j] : ((d == 1) ? ny[j] : nz[j]);
      float c1 = (d == 0) ? nx[j + 8] : ((d == 1) ? ny[j + 8] : nz[j + 8]);
      float e0 = __fsub_rn(c0, pc);
      float e1 = __fsub_rn(c1, pc);
      r[j] = __fadd_rn(__fmul_rn(e0, e0), __fmul_rn(e1, e1));
    }
    float t0 = __fadd_rn(r[0], r[1]);
    float t1 = __fadd_rn(r[2], r[3]);
    float t2 = __fadd_rn(r[4], r[5]);
    float t3 = __fadd_rn(r[6], r[7]);
    P[d] = __fadd_rn(__fadd_rn(t0, t1), __fadd_rn(t2, t3));
  }
  score[(size_t)b * NPTS + n] =
      __fadd_rn(__fadd_rn(P[0], P[1]), P[2]);
}

// ---------------------------------------------------------------------------
// Kernel 2a: zero the rank counters (kernel instead of memset: capture-safe).
// ---------------------------------------------------------------------------
__global__ __launch_bounds__(256) void zero_kernel(int* __restrict__ cnt) {
  cnt[blockIdx.x * 256 + threadIdx.x] = 0;
}

// ---------------------------------------------------------------------------
// Kernel 2b: partial counting rank over an m-chunk, atomicAdd into cnt.
// rank(n) = #{m : s[m]>s[n] or (s[m]==s[n] and m<n)} == stable desc argsort.
// ---------------------------------------------------------------------------
__global__ __launch_bounds__(256) void rank_partial_kernel(
    const float* __restrict__ score, int* __restrict__ cnt) {
  const int s = blockIdx.x % RSPLIT;
  const int ntile = (blockIdx.x / RSPLIT) % (NPTS / 256);
  const int b = blockIdx.x / (RSPLIT * (NPTS / 256));
  __shared__ float ss[RCHUNK];

  const float* sb = score + (size_t)b * NPTS;
  for (int i = threadIdx.x; i < RCHUNK; i += 256)
    ss[i] = sb[s * RCHUNK + i];

  const int n = ntile * 256 + threadIdx.x;
  const float sn = sb[n];
  __syncthreads();

  int c = 0;
#pragma unroll 8
  for (int mm = 0; mm < RCHUNK; ++mm) {
    float sm = ss[mm];
    int gm = s * RCHUNK + mm;
    c += (sm > sn) || (sm == sn && gm < n);
  }
  atomicAdd(&cnt[(size_t)b * NPTS + n], c);
}

// ---------------------------------------------------------------------------
// Kernel 2c: scatter selected points into rank order.
// ---------------------------------------------------------------------------
__global__ __launch_bounds__(256) void rank_scatter_kernel(
    const int* __restrict__ cnt, int* __restrict__ sel, int npts) {
  int t = blockIdx.x * 256 + threadIdx.x;  // over BATCH*NPTS
  int b = t / NPTS;
  int n = t % NPTS;
  int c = cnt[t];
  if (c < npts) sel[(size_t)b * npts + c] = n;
}

// ---------------------------------------------------------------------------
// Kernel 3: gather xyz then features into the concatenated flat output.
// ---------------------------------------------------------------------------
__global__ __launch_bounds__(256) void gather_kernel(
    const float* __restrict__ x, const float* __restrict__ y,
    const int* __restrict__ sel, float* __restrict__ out, int npts,
    int total0, int total) {
  int tid = blockIdx.x * blockDim.x + threadIdx.x;
  if (tid >= total) return;
  if (tid < total0) {
    int j = tid % npts;
    int rest = tid / npts;
    int d = rest % 3;
    int b = rest / 3;
    int src = sel[b * npts + j];
    out[tid] = x[((size_t)b * 3 + d) * NPTS + src];
  } else {
    int t = tid - total0;
    int j = t % npts;
    int rest = t / npts;
    int c = rest % CHAN;
    int b = rest / CHAN;
    int src = sel[b * npts + j];
    out[tid] = y[((size_t)b * CHAN + c) * NPTS + src];
  }
}

extern "C" void kernel_launch(void* const* d_in, const int* in_sizes, int n_in,
                              void* d_out, int out_size, void* d_ws,
                              size_t ws_size, hipStream_t stream) {
  const float* x = (const float*)d_in[0];
  const float* y = (const float*)d_in[1];
  float* out = (float*)d_out;

  const int npts = out_size / (BATCH * (3 + CHAN));

  // workspace layout:
  char* w = (char*)d_ws;
  u64* pkey = (u64*)w;                       // B*S*16*N u64 = 16.78 MB
  w += sizeof(u64) * (size_t)BATCH * SPLIT * KNN * NPTS;
  float* score = (float*)w;                  // B*N f32
  w += sizeof(float) * (size_t)BATCH * NPTS;
  int* cnt = (int*)w;                        // B*N i32
  w += sizeof(int) * (size_t)BATCH * NPTS;
  int* sel = (int*)w;                        // B*npts i32

  zero_kernel<<<BATCH * NPTS / 256, 256, 0, stream>>>(cnt);
  knn_partial_kernel<<<BATCH * (NPTS / 256) * SPLIT, 256, 0, stream>>>(
      x, pkey);
  merge_score_kernel<<<BATCH * NPTS / 256, 256, 0, stream>>>(x, pkey, score);
  rank_partial_kernel<<<BATCH * (NPTS / 256) * RSPLIT, 256, 0, stream>>>(
      score, cnt);
  rank_scatter_kernel<<<BATCH * NPTS / 256, 256, 0, stream>>>(cnt, sel, npts);

  const int total0 = BATCH * 3 * npts;
  gather_kernel<<<(out_size + 255) / 256, 256, 0, stream>>>(
      x, y, sel, out, npts, total0, out_size);
}

// Round 6
// 487.408 us; speedup vs baseline: 4.2475x; 1.0686x over previous
//
#include <hip/hip_runtime.h>
#include <math.h>

#define BATCH 8
#define NPTS 4096
#define CHAN 128
#define KNN 16
#define SPLIT 4
#define CHUNK (NPTS / SPLIT)   // 1024 points, 16 KB LDS
#define RSPLIT 4
#define RCHUNK (NPTS / RSPLIT) // 1024 scores, 4 KB LDS

typedef unsigned long long u64;

// Monotone key: ascending u64 == (d2 ascending, idx ascending).
// Ties in d2 break toward lower index == lax.top_k stable order.
__device__ __forceinline__ u64 pack_key(float d2, int idx) {
  unsigned b = __float_as_uint(d2);
  b ^= (unsigned)((int)b >> 31) | 0x80000000u;  // order-preserving fp32 map
  return ((u64)b << 32) | (unsigned)idx;
}

// Fully branchless sorted insert (ascending k0..k15). All compares up front
// (reused lane masks), then pure select chains — no control flow.
// Slot update reads only not-yet-written slots (descending order).
#define INSERT_KU(ku)                                                     \
  do {                                                                    \
    const u64 _u = (ku);                                                  \
    bool c0 = _u < k0, c1 = _u < k1, c2 = _u < k2, c3 = _u < k3;          \
    bool c4 = _u < k4, c5 = _u < k5, c6 = _u < k6, c7 = _u < k7;          \
    bool c8 = _u < k8, c9 = _u < k9, c10 = _u < k10, c11 = _u < k11;      \
    bool c12 = _u < k12, c13 = _u < k13, c14 = _u < k14, c15 = _u < k15;  \
    k15 = c14 ? k14 : (c15 ? _u : k15);                                   \
    k14 = c13 ? k13 : (c14 ? _u : k14);                                   \
    k13 = c12 ? k12 : (c13 ? _u : k13);                                   \
    k12 = c11 ? k11 : (c12 ? _u : k12);                                   \
    k11 = c10 ? k10 : (c11 ? _u : k11);                                   \
    k10 = c9 ? k9 : (c10 ? _u : k10);                                     \
    k9 = c8 ? k8 : (c9 ? _u : k9);                                        \
    k8 = c7 ? k7 : (c8 ? _u : k8);                                        \
    k7 = c6 ? k6 : (c7 ? _u : k7);                                        \
    k6 = c5 ? k5 : (c6 ? _u : k6);                                        \
    k5 = c4 ? k4 : (c5 ? _u : k5);                                        \
    k4 = c3 ? k3 : (c4 ? _u : k4);                                        \
    k3 = c2 ? k2 : (c3 ? _u : k3);                                        \
    k2 = c1 ? k1 : (c2 ? _u : k2);                                        \
    k1 = c0 ? k0 : (c1 ? _u : k1);                                        \
    k0 = c0 ? _u : k0;                                                    \
  } while (0)

#define DECL_KEYS                                                         \
  u64 k0 = ~0ull, k1 = ~0ull, k2 = ~0ull, k3 = ~0ull, k4 = ~0ull,         \
      k5 = ~0ull, k6 = ~0ull, k7 = ~0ull, k8 = ~0ull, k9 = ~0ull,         \
      k10 = ~0ull, k11 = ~0ull, k12 = ~0ull, k13 = ~0ull, k14 = ~0ull,    \
      k15 = ~0ull

// ---------------------------------------------------------------------------
// Kernel 1a: per-chunk 16-NN partials as sorted u64 keys.
// grid: BATCH * (NPTS/256) * SPLIT = 512 blocks = 2 blocks/CU = 2 waves/EU.
// amdgpu_waves_per_eu(2,2): pins the allocator's occupancy TARGET (not just
// the launch_bounds minimum) -> ~256 VGPR budget -> 16-key state stays in
// arch VGPRs. Rounds 3-5: default target made it spill (scratch / AGPR
// shuffle: VGPR_Count 24-36, +~100 VALU/iter of v_accvgpr traffic).
// ---------------------------------------------------------------------------
__global__ __attribute__((amdgpu_waves_per_eu(2, 2)))
__launch_bounds__(256) void knn_partial_kernel(
    const float* __restrict__ x, u64* __restrict__ pkey) {
  const int s = blockIdx.x % SPLIT;
  const int ntile = (blockIdx.x / SPLIT) % (NPTS / 256);
  const int b = blockIdx.x / (SPLIT * (NPTS / 256));
  __shared__ float4 xs[CHUNK];  // (x, y, z, sq)

  const float* xb = x + (size_t)b * 3 * NPTS;
  for (int i = threadIdx.x; i < CHUNK; i += 256) {
    int gm = s * CHUNK + i;
    float px = xb[gm];
    float py = xb[NPTS + gm];
    float pz = xb[2 * NPTS + gm];
    float sq = __fadd_rn(__fadd_rn(__fmul_rn(px, px), __fmul_rn(py, py)),
                         __fmul_rn(pz, pz));
    xs[i] = make_float4(px, py, pz, sq);
  }

  const int n = ntile * 256 + threadIdx.x;
  float ppx = xb[n];
  float ppy = xb[NPTS + n];
  float ppz = xb[2 * NPTS + n];
  float psq = __fadd_rn(__fadd_rn(__fmul_rn(ppx, ppx), __fmul_rn(ppy, ppy)),
                        __fmul_rn(ppz, ppz));
  __syncthreads();

  DECL_KEYS;

#pragma unroll 4
  for (int mm = 0; mm < CHUNK; ++mm) {
    float4 q = xs[mm];
    // inner = ((x0*y0 + x1*y1) + x2*y2), fp32, no fma (numpy einsum order)
    float inner = __fadd_rn(
        __fadd_rn(__fmul_rn(ppx, q.x), __fmul_rn(ppy, q.y)),
        __fmul_rn(ppz, q.z));
    // d2 = (sq_n + sq_m) - 2*inner  (reference formula, pinned rounding)
    float d2 = __fsub_rn(__fadd_rn(psq, q.w), __fmul_rn(2.0f, inner));
    u64 ku = pack_key(d2, s * CHUNK + mm);
    INSERT_KU(ku);
  }

  u64* pb = pkey + ((size_t)(b * SPLIT + s) * KNN) * NPTS + n;
  pb[0 * NPTS] = k0;   pb[1 * NPTS] = k1;   pb[2 * NPTS] = k2;
  pb[3 * NPTS] = k3;   pb[4 * NPTS] = k4;   pb[5 * NPTS] = k5;
  pb[6 * NPTS] = k6;   pb[7 * NPTS] = k7;   pb[8 * NPTS] = k8;
  pb[9 * NPTS] = k9;   pb[10 * NPTS] = k10; pb[11 * NPTS] = k11;
  pb[12 * NPTS] = k12; pb[13 * NPTS] = k13; pb[14 * NPTS] = k14;
  pb[15 * NPTS] = k15;
}

// ---------------------------------------------------------------------------
// Kernel 1b: merge SPLIT sorted key lists -> global top-16, then fp32 score
// with numpy's pairwise order (validated round 2). Keys unique -> insertion
// order irrelevant -> exactness holds.
// grid: BATCH*NPTS/256 = 128 blocks. Same waves_per_eu pin (16-key state).
// ---------------------------------------------------------------------------
__global__ __attribute__((amdgpu_waves_per_eu(1, 2)))
__launch_bounds__(256) void merge_score_kernel(
    const float* __restrict__ x, const u64* __restrict__ pkey,
    float* __restrict__ score) {
  const int b = blockIdx.x / (NPTS / 256);
  const int n = (blockIdx.x % (NPTS / 256)) * 256 + threadIdx.x;

  DECL_KEYS;

#pragma unroll
  for (int s = 0; s < SPLIT; ++s) {
    const u64* pb = pkey + ((size_t)(b * SPLIT + s) * KNN) * NPTS + n;
#pragma unroll
    for (int j = 0; j < KNN; ++j) {
      u64 ku = pb[(size_t)j * NPTS];
      INSERT_KU(ku);
    }
  }

  int idxv[KNN];
  idxv[0] = (int)(unsigned)k0;   idxv[1] = (int)(unsigned)k1;
  idxv[2] = (int)(unsigned)k2;   idxv[3] = (int)(unsigned)k3;
  idxv[4] = (int)(unsigned)k4;   idxv[5] = (int)(unsigned)k5;
  idxv[6] = (int)(unsigned)k6;   idxv[7] = (int)(unsigned)k7;
  idxv[8] = (int)(unsigned)k8;   idxv[9] = (int)(unsigned)k9;
  idxv[10] = (int)(unsigned)k10; idxv[11] = (int)(unsigned)k11;
  idxv[12] = (int)(unsigned)k12; idxv[13] = (int)(unsigned)k13;
  idxv[14] = (int)(unsigned)k14; idxv[15] = (int)(unsigned)k15;

  const float* xb = x + (size_t)b * 3 * NPTS;
  float ppx = xb[n];
  float ppy = xb[NPTS + n];
  float ppz = xb[2 * NPTS + n];

  float nx[KNN], ny[KNN], nz[KNN];
#pragma unroll
  for (int j = 0; j < KNN; ++j) {
    int idx = idxv[j];
    nx[j] = xb[idx];
    ny[j] = xb[NPTS + idx];
    nz[j] = xb[2 * NPTS + idx];
  }

  // numpy fp32 pairwise sum over (3,16): per d, r_j = a_j + a_{j+8},
  // P_d = ((r0+r1)+(r2+r3)) + ((r4+r5)+(r6+r7)); score = (P0+P1)+P2.
  float P[3];
#pragma unroll
  for (int d = 0; d < 3; ++d) {
    const float pc = (d == 0) ? ppx : ((d == 1) ? ppy : ppz);
    float r[8];
#pragma unroll
    for (int j = 0; j < 8; ++j) {
      float c0 = (d == 0) ? nx[j] : ((d == 1) ? ny[j] : nz[j]);
      float c1 = (d == 0) ? nx[j + 8] : ((d == 1) ? ny[j + 8] : nz[j + 8]);
      float e0 = __fsub_rn(c0, pc);
      float e1 = __fsub_rn(c1, pc);
      r[j] = __fadd_rn(__fmul_rn(e0, e0), __fmul_rn(e1, e1));
    }
    float t0 = __fadd_rn(r[0], r[1]);
    float t1 = __fadd_rn(r[2], r[3]);
    float t2 = __fadd_rn(r[4], r[5]);
    float t3 = __fadd_rn(r[6], r[7]);
    P[d] = __fadd_rn(__fadd_rn(t0, t1), __fadd_rn(t2, t3));
  }
  score[(size_t)b * NPTS + n] =
      __fadd_rn(__fadd_rn(P[0], P[1]), P[2]);
}

// ---------------------------------------------------------------------------
// Kernel 2a: zero the rank counters (kernel instead of memset: capture-safe).
// ---------------------------------------------------------------------------
__global__ __launch_bounds__(256) void zero_kernel(int* __restrict__ cnt) {
  cnt[blockIdx.x * 256 + threadIdx.x] = 0;
}

// ---------------------------------------------------------------------------
// Kernel 2b: partial counting rank over an m-chunk, atomicAdd into cnt.
// rank(n) = #{m : s[m]>s[n] or (s[m]==s[n] and m<n)} == stable desc argsort.
// ---------------------------------------------------------------------------
__global__ __launch_bounds__(256) void rank_partial_kernel(
    const float* __restrict__ score, int* __restrict__ cnt) {
  const int s = blockIdx.x % RSPLIT;
  const int ntile = (blockIdx.x / RSPLIT) % (NPTS / 256);
  const int b = blockIdx.x / (RSPLIT * (NPTS / 256));
  __shared__ float ss[RCHUNK];

  const float* sb = score + (size_t)b * NPTS;
  for (int i = threadIdx.x; i < RCHUNK; i += 256)
    ss[i] = sb[s * RCHUNK + i];

  const int n = ntile * 256 + threadIdx.x;
  const float sn = sb[n];
  __syncthreads();

  int c = 0;
#pragma unroll 8
  for (int mm = 0; mm < RCHUNK; ++mm) {
    float sm = ss[mm];
    int gm = s * RCHUNK + mm;
    c += (sm > sn) || (sm == sn && gm < n);
  }
  atomicAdd(&cnt[(size_t)b * NPTS + n], c);
}

// ---------------------------------------------------------------------------
// Kernel 2c: scatter selected points into rank order.
// ---------------------------------------------------------------------------
__global__ __launch_bounds__(256) void rank_scatter_kernel(
    const int* __restrict__ cnt, int* __restrict__ sel, int npts) {
  int t = blockIdx.x * 256 + threadIdx.x;  // over BATCH*NPTS
  int b = t / NPTS;
  int n = t % NPTS;
  int c = cnt[t];
  if (c < npts) sel[(size_t)b * npts + c] = n;
}

// ---------------------------------------------------------------------------
// Kernel 3: gather xyz then features into the concatenated flat output.
// ---------------------------------------------------------------------------
__global__ __launch_bounds__(256) void gather_kernel(
    const float* __restrict__ x, const float* __restrict__ y,
    const int* __restrict__ sel, float* __restrict__ out, int npts,
    int total0, int total) {
  int tid = blockIdx.x * blockDim.x + threadIdx.x;
  if (tid >= total) return;
  if (tid < total0) {
    int j = tid % npts;
    int rest = tid / npts;
    int d = rest % 3;
    int b = rest / 3;
    int src = sel[b * npts + j];
    out[tid] = x[((size_t)b * 3 + d) * NPTS + src];
  } else {
    int t = tid - total0;
    int j = t % npts;
    int rest = t / npts;
    int c = rest % CHAN;
    int b = rest / CHAN;
    int src = sel[b * npts + j];
    out[tid] = y[((size_t)b * CHAN + c) * NPTS + src];
  }
}

extern "C" void kernel_launch(void* const* d_in, const int* in_sizes, int n_in,
                              void* d_out, int out_size, void* d_ws,
                              size_t ws_size, hipStream_t stream) {
  const float* x = (const float*)d_in[0];
  const float* y = (const float*)d_in[1];
  float* out = (float*)d_out;

  const int npts = out_size / (BATCH * (3 + CHAN));

  // workspace layout:
  char* w = (char*)d_ws;
  u64* pkey = (u64*)w;                       // B*S*16*N u64 = 16.78 MB
  w += sizeof(u64) * (size_t)BATCH * SPLIT * KNN * NPTS;
  float* score = (float*)w;                  // B*N f32
  w += sizeof(float) * (size_t)BATCH * NPTS;
  int* cnt = (int*)w;                        // B*N i32
  w += sizeof(int) * (size_t)BATCH * NPTS;
  int* sel = (int*)w;                        // B*npts i32

  zero_kernel<<<BATCH * NPTS / 256, 256, 0, stream>>>(cnt);
  knn_partial_kernel<<<BATCH * (NPTS / 256) * SPLIT, 256, 0, stream>>>(
      x, pkey);
  merge_score_kernel<<<BATCH * NPTS / 256, 256, 0, stream>>>(x, pkey, score);
  rank_partial_kernel<<<BATCH * (NPTS / 256) * RSPLIT, 256, 0, stream>>>(
      score, cnt);
  rank_scatter_kernel<<<BATCH * NPTS / 256, 256, 0, stream>>>(cnt, sel, npts);

  const int total0 = BATCH * 3 * npts;
  gather_kernel<<<(out_size + 255) / 256, 256, 0, stream>>>(
      x, y, sel, out, npts, total0, out_size);
}

// Round 7
// 325.040 us; speedup vs baseline: 6.3693x; 1.4995x over previous
//
#include <hip/hip_runtime.h>
#include <math.h>

#define BATCH 8
#define NPTS 4096
#define CHAN 128
#define KNN 16
#define SPLIT 4
#define CHUNK (NPTS / SPLIT)   // 1024 points, 16 KB LDS
#define RSPLIT 4
#define RCHUNK (NPTS / RSPLIT) // 1024 scores, 4 KB LDS

typedef unsigned long long u64;

// Monotone key: ascending u64 == (d2 ascending, idx ascending).
// Ties in d2 break toward lower index == lax.top_k stable order.
__device__ __forceinline__ u64 pack_key(float d2, int idx) {
  unsigned b = __float_as_uint(d2);
  b ^= (unsigned)((int)b >> 31) | 0x80000000u;  // order-preserving fp32 map
  return ((u64)b << 32) | (unsigned)idx;
}

// Compare-exchange: after call x <= y. 1 v_cmp_lt_u64 + 4 v_cndmask.
__device__ __forceinline__ void ce_asc(u64& x, u64& y) {
  bool sw = y < x;
  u64 lo = sw ? y : x;
  u64 hi = sw ? x : y;
  x = lo;
  y = hi;
}

// Bitonic sort of 16 u64 keys, ascending. 80 CE, fully unrolled,
// constant indices -> register-resident.
__device__ __forceinline__ void bitonic_sort16(u64 a[16]) {
#pragma unroll
  for (int k = 2; k <= 16; k <<= 1) {
#pragma unroll
    for (int j = k >> 1; j > 0; j >>= 1) {
#pragma unroll
      for (int i = 0; i < 16; ++i) {
        int l = i ^ j;
        if (l > i) {
          if ((i & k) == 0) ce_asc(a[i], a[l]);
          else              ce_asc(a[l], a[i]);
        }
      }
    }
  }
}

// T, A both sorted ascending. T <- lowest-16 of (T ∪ A), sorted ascending.
// Identity: nt_i = min(T_i, A_rev_i) is the lowest-16 multiset, bitonic;
// 4-stage bitonic merge cleans it. 16 min + 32 CE.
__device__ __forceinline__ void merge_keep16(u64 T[16], const u64 A[16]) {
  u64 nt[16];
#pragma unroll
  for (int i = 0; i < 16; ++i) {
    u64 a = A[15 - i];
    nt[i] = (a < T[i]) ? a : T[i];
  }
#pragma unroll
  for (int j = 8; j > 0; j >>= 1) {
#pragma unroll
    for (int i = 0; i < 16; ++i) {
      int l = i ^ j;
      if (l > i) ce_asc(nt[i], nt[l]);
    }
  }
#pragma unroll
  for (int i = 0; i < 16; ++i) T[i] = nt[i];
}

// ---------------------------------------------------------------------------
// Kernel 1a: per-chunk 16-NN partials as sorted u64 keys.
// grid: BATCH * (NPTS/256) * SPLIT = 512 blocks = 2 blocks/CU = 2 waves/EU.
// amdgpu_waves_per_eu(2,2) pins allocator occupancy target -> key arrays in
// arch VGPRs (round 6: VGPR 28->88 proved the knob works).
// Batched bitonic (G=16): sort16 + merge-keep16 ≈ 51 VALU/candidate vs ~185
// measured for the per-candidate insertion chain (round 6).
// ---------------------------------------------------------------------------
__global__ __attribute__((amdgpu_waves_per_eu(2, 2)))
__launch_bounds__(256) void knn_partial_kernel(
    const float* __restrict__ x, u64* __restrict__ pkey) {
  const int s = blockIdx.x % SPLIT;
  const int ntile = (blockIdx.x / SPLIT) % (NPTS / 256);
  const int b = blockIdx.x / (SPLIT * (NPTS / 256));
  __shared__ float4 xs[CHUNK];  // (x, y, z, sq)

  const float* xb = x + (size_t)b * 3 * NPTS;
  for (int i = threadIdx.x; i < CHUNK; i += 256) {
    int gm = s * CHUNK + i;
    float px = xb[gm];
    float py = xb[NPTS + gm];
    float pz = xb[2 * NPTS + gm];
    float sq = __fadd_rn(__fadd_rn(__fmul_rn(px, px), __fmul_rn(py, py)),
                         __fmul_rn(pz, pz));
    xs[i] = make_float4(px, py, pz, sq);
  }

  const int n = ntile * 256 + threadIdx.x;
  float ppx = xb[n];
  float ppy = xb[NPTS + n];
  float ppz = xb[2 * NPTS + n];
  float psq = __fadd_rn(__fadd_rn(__fmul_rn(ppx, ppx), __fmul_rn(ppy, ppy)),
                        __fmul_rn(ppz, ppz));
  __syncthreads();

  u64 T[16];
#pragma unroll
  for (int i = 0; i < 16; ++i) T[i] = ~0ull;  // sentinel > any real key

  for (int base = 0; base < CHUNK; base += 16) {
    u64 A[16];
#pragma unroll
    for (int t = 0; t < 16; ++t) {
      float4 q = xs[base + t];
      // inner = ((x0*y0 + x1*y1) + x2*y2), fp32, no fma (numpy einsum order)
      float inner = __fadd_rn(
          __fadd_rn(__fmul_rn(ppx, q.x), __fmul_rn(ppy, q.y)),
          __fmul_rn(ppz, q.z));
      // d2 = (sq_n + sq_m) - 2*inner  (reference formula, pinned rounding)
      float d2 = __fsub_rn(__fadd_rn(psq, q.w), __fmul_rn(2.0f, inner));
      A[t] = pack_key(d2, s * CHUNK + base + t);
    }
    bitonic_sort16(A);
    merge_keep16(T, A);
  }

  u64* pb = pkey + ((size_t)(b * SPLIT + s) * KNN) * NPTS + n;
#pragma unroll
  for (int j = 0; j < 16; ++j) pb[(size_t)j * NPTS] = T[j];
}

// ---------------------------------------------------------------------------
// Kernel 1b: merge SPLIT sorted key lists -> global top-16, then fp32 score
// with numpy's pairwise order (validated round 2). Keys unique -> order of
// merging irrelevant -> exactness holds. Lists arrive sorted: 3x
// merge_keep16, no insertion chains.
// grid: BATCH*NPTS/256 = 128 blocks.
// ---------------------------------------------------------------------------
__global__ __attribute__((amdgpu_waves_per_eu(1, 2)))
__launch_bounds__(256) void merge_score_kernel(
    const float* __restrict__ x, const u64* __restrict__ pkey,
    float* __restrict__ score) {
  const int b = blockIdx.x / (NPTS / 256);
  const int n = (blockIdx.x % (NPTS / 256)) * 256 + threadIdx.x;

  u64 T[16];
  {
    const u64* pb = pkey + ((size_t)(b * SPLIT + 0) * KNN) * NPTS + n;
#pragma unroll
    for (int j = 0; j < 16; ++j) T[j] = pb[(size_t)j * NPTS];
  }
#pragma unroll
  for (int s = 1; s < SPLIT; ++s) {
    const u64* pb = pkey + ((size_t)(b * SPLIT + s) * KNN) * NPTS + n;
    u64 A[16];
#pragma unroll
    for (int j = 0; j < 16; ++j) A[j] = pb[(size_t)j * NPTS];
    merge_keep16(T, A);
  }

  const float* xb = x + (size_t)b * 3 * NPTS;
  float ppx = xb[n];
  float ppy = xb[NPTS + n];
  float ppz = xb[2 * NPTS + n];

  float nx[KNN], ny[KNN], nz[KNN];
#pragma unroll
  for (int j = 0; j < KNN; ++j) {
    int idx = (int)(unsigned)T[j];
    nx[j] = xb[idx];
    ny[j] = xb[NPTS + idx];
    nz[j] = xb[2 * NPTS + idx];
  }

  // numpy fp32 pairwise sum over (3,16): per d, r_j = a_j + a_{j+8},
  // P_d = ((r0+r1)+(r2+r3)) + ((r4+r5)+(r6+r7)); score = (P0+P1)+P2.
  float P[3];
#pragma unroll
  for (int d = 0; d < 3; ++d) {
    const float pc = (d == 0) ? ppx : ((d == 1) ? ppy : ppz);
    float r[8];
#pragma unroll
    for (int j = 0; j < 8; ++j) {
      float c0 = (d == 0) ? nx[j] : ((d == 1) ? ny[j] : nz[j]);
      float c1 = (d == 0) ? nx[j + 8] : ((d == 1) ? ny[j + 8] : nz[j + 8]);
      float e0 = __fsub_rn(c0, pc);
      float e1 = __fsub_rn(c1, pc);
      r[j] = __fadd_rn(__fmul_rn(e0, e0), __fmul_rn(e1, e1));
    }
    float t0 = __fadd_rn(r[0], r[1]);
    float t1 = __fadd_rn(r[2], r[3]);
    float t2 = __fadd_rn(r[4], r[5]);
    float t3 = __fadd_rn(r[6], r[7]);
    P[d] = __fadd_rn(__fadd_rn(t0, t1), __fadd_rn(t2, t3));
  }
  score[(size_t)b * NPTS + n] =
      __fadd_rn(__fadd_rn(P[0], P[1]), P[2]);
}

// ---------------------------------------------------------------------------
// Kernel 2a: zero the rank counters (kernel instead of memset: capture-safe).
// ---------------------------------------------------------------------------
__global__ __launch_bounds__(256) void zero_kernel(int* __restrict__ cnt) {
  cnt[blockIdx.x * 256 + threadIdx.x] = 0;
}

// ---------------------------------------------------------------------------
// Kernel 2b: partial counting rank over an m-chunk, atomicAdd into cnt.
// rank(n) = #{m : s[m]>s[n] or (s[m]==s[n] and m<n)} == stable desc argsort.
// ---------------------------------------------------------------------------
__global__ __launch_bounds__(256) void rank_partial_kernel(
    const float* __restrict__ score, int* __restrict__ cnt) {
  const int s = blockIdx.x % RSPLIT;
  const int ntile = (blockIdx.x / RSPLIT) % (NPTS / 256);
  const int b = blockIdx.x / (RSPLIT * (NPTS / 256));
  __shared__ float ss[RCHUNK];

  const float* sb = score + (size_t)b * NPTS;
  for (int i = threadIdx.x; i < RCHUNK; i += 256)
    ss[i] = sb[s * RCHUNK + i];

  const int n = ntile * 256 + threadIdx.x;
  const float sn = sb[n];
  __syncthreads();

  int c = 0;
#pragma unroll 8
  for (int mm = 0; mm < RCHUNK; ++mm) {
    float sm = ss[mm];
    int gm = s * RCHUNK + mm;
    c += (sm > sn) || (sm == sn && gm < n);
  }
  atomicAdd(&cnt[(size_t)b * NPTS + n], c);
}

// ---------------------------------------------------------------------------
// Kernel 2c: scatter selected points into rank order.
// ---------------------------------------------------------------------------
__global__ __launch_bounds__(256) void rank_scatter_kernel(
    const int* __restrict__ cnt, int* __restrict__ sel, int npts) {
  int t = blockIdx.x * 256 + threadIdx.x;  // over BATCH*NPTS
  int b = t / NPTS;
  int n = t % NPTS;
  int c = cnt[t];
  if (c < npts) sel[(size_t)b * npts + c] = n;
}

// ---------------------------------------------------------------------------
// Kernel 3: gather xyz then features into the concatenated flat output.
// ---------------------------------------------------------------------------
__global__ __launch_bounds__(256) void gather_kernel(
    const float* __restrict__ x, const float* __restrict__ y,
    const int* __restrict__ sel, float* __restrict__ out, int npts,
    int total0, int total) {
  int tid = blockIdx.x * blockDim.x + threadIdx.x;
  if (tid >= total) return;
  if (tid < total0) {
    int j = tid % npts;
    int rest = tid / npts;
    int d = rest % 3;
    int b = rest / 3;
    int src = sel[b * npts + j];
    out[tid] = x[((size_t)b * 3 + d) * NPTS + src];
  } else {
    int t = tid - total0;
    int j = t % npts;
    int rest = t / npts;
    int c = rest % CHAN;
    int b = rest / CHAN;
    int src = sel[b * npts + j];
    out[tid] = y[((size_t)b * CHAN + c) * NPTS + src];
  }
}

extern "C" void kernel_launch(void* const* d_in, const int* in_sizes, int n_in,
                              void* d_out, int out_size, void* d_ws,
                              size_t ws_size, hipStream_t stream) {
  const float* x = (const float*)d_in[0];
  const float* y = (const float*)d_in[1];
  float* out = (float*)d_out;

  const int npts = out_size / (BATCH * (3 + CHAN));

  // workspace layout:
  char* w = (char*)d_ws;
  u64* pkey = (u64*)w;                       // B*S*16*N u64 = 16.78 MB
  w += sizeof(u64) * (size_t)BATCH * SPLIT * KNN * NPTS;
  float* score = (float*)w;                  // B*N f32
  w += sizeof(float) * (size_t)BATCH * NPTS;
  int* cnt = (int*)w;                        // B*N i32
  w += sizeof(int) * (size_t)BATCH * NPTS;
  int* sel = (int*)w;                        // B*npts i32

  zero_kernel<<<BATCH * NPTS / 256, 256, 0, stream>>>(cnt);
  knn_partial_kernel<<<BATCH * (NPTS / 256) * SPLIT, 256, 0, stream>>>(
      x, pkey);
  merge_score_kernel<<<BATCH * NPTS / 256, 256, 0, stream>>>(x, pkey, score);
  rank_partial_kernel<<<BATCH * (NPTS / 256) * RSPLIT, 256, 0, stream>>>(
      score, cnt);
  rank_scatter_kernel<<<BATCH * NPTS / 256, 256, 0, stream>>>(cnt, sel, npts);

  const int total0 = BATCH * 3 * npts;
  gather_kernel<<<(out_size + 255) / 256, 256, 0, stream>>>(
      x, y, sel, out, npts, total0, out_size);
}